// Round 3
// baseline (3310.133 us; speedup 1.0000x reference)
//
#include <hip/hip_runtime.h>
#include <math.h>

#define THREADS 256

// Dims: B=8, C(seq)=10, F(dim)=48, H=W=64, HEADS=8, hd=6, MLP=192
// Stage2: NI=80 images, CH=96, PW=384, OUTF=48

// ---------------- Kernel A: fused 2-layer transformer, 4 sequences/block ----------------
// LDS: tbuf 7.7KB + sbuf 30.7KB = 38.4KB -> 4 blocks/CU
// blockIdx swizzle: b = blk&7 (== XCD under round-robin), so each XCD streams one
// contiguous image of x -> full 128B-line utilization (fixes 8x x over-fetch).
__global__ __launch_bounds__(THREADS, 4) void ka_transformer(
    const float* __restrict__ x,
    const float* __restrict__ qkv_w, const float* __restrict__ qkv_b,
    const float* __restrict__ proj_w, const float* __restrict__ proj_b,
    const float* __restrict__ ff1_w, const float* __restrict__ ff1_b,
    const float* __restrict__ ff2_w, const float* __restrict__ ff2_b,
    float* __restrict__ t_out)
{
    __shared__ float tbuf[1920];   // [s*480 + c*48 + f] == flat token m=s*10+c at m*48 (m<40)
    __shared__ float sbuf[7680];   // qkv: [m*144+o] ; attn-out: [m*48+hd] ; h1: [m*192+j]
    const int tid = threadIdx.x;
    const int blk = blockIdx.x;          // 8192 blocks
    const int b   = blk & 7;             // XCD-aligned image
    const int hw0 = (blk >> 3) << 2;     // 4 pixels per block, contiguous per XCD

    // stage: tbuf[s*480+cf] = x[(b*480+cf)*4096 + hw0 + s], via float4 over s
    for (int cf = tid; cf < 480; cf += THREADS) {
        const float4 v = *(const float4*)(x + ((size_t)(b * 480 + cf)) * 4096 + hw0);
        tbuf[cf] = v.x; tbuf[480 + cf] = v.y; tbuf[960 + cf] = v.z; tbuf[1440 + cf] = v.w;
    }
    __syncthreads();

    for (int l = 0; l < 2; ++l) {
        const float* qw  = qkv_w + l * 6912;
        const float* qb  = qkv_b + l * 144;
        const float* pw  = proj_w + l * 2304;
        const float* pb  = proj_b + l * 48;
        const float* f1w = ff1_w + l * 9216;
        const float* f1b = ff1_b + l * 192;
        const float* f2w = ff2_w + l * 9216;
        const float* f2b = ff2_b + l * 48;

        // ---- qkv: 40x144, 240 tasks of 2 rows x 12 cols, K=48 (aligned f4 weights) ----
        if (tid < 240) {
            const int og = tid % 12, mg = tid / 12;
            const int o0 = og * 12, m0 = mg * 2;
            const float* trow = tbuf + m0 * 48;
            float acc[2][12] = {};
            for (int k = 0; k < 48; k += 4) {
                float4 a0 = *(const float4*)(trow + k);
                float4 a1 = *(const float4*)(trow + 48 + k);
                #pragma unroll
                for (int kk = 0; kk < 4; ++kk) {
                    const float* wr = qw + (k + kk) * 144 + o0;
                    float4 w0 = *(const float4*)(wr);
                    float4 w1 = *(const float4*)(wr + 4);
                    float4 w2 = *(const float4*)(wr + 8);
                    float wv[12];
                    *(float4*)(wv) = w0; *(float4*)(wv + 4) = w1; *(float4*)(wv + 8) = w2;
                    const float e0 = (&a0.x)[kk], e1 = (&a1.x)[kk];
                    #pragma unroll
                    for (int c = 0; c < 12; ++c) {
                        acc[0][c] += e0 * wv[c]; acc[1][c] += e1 * wv[c];
                    }
                }
            }
            #pragma unroll
            for (int r = 0; r < 2; ++r)
                #pragma unroll
                for (int c = 0; c < 12; ++c)
                    sbuf[(m0 + r) * 144 + o0 + c] = acc[r][c] + qb[o0 + c];
        }
        __syncthreads();

        // ---- banded attention: 4 seq x 10 i x 8 h = 320 tasks ----
        float ores[2][6];
        #pragma unroll
        for (int it = 0; it < 2; ++it) {
            int task = tid + it * THREADS;
            if (task < 320) {
                int s = task / 80, r = task % 80, i = r / 8, h = r % 8;
                const float* base = sbuf + s * 1440 + h * 6;
                float kv[6];
                #pragma unroll
                for (int d = 0; d < 6; ++d) kv[d] = base[i * 144 + 48 + d];
                int jlo = (i > 0) ? i - 1 : 0;
                int jhi = (i < 9) ? i + 1 : 9;
                float lg[3], mx = -3.4e38f;
                for (int j = jlo; j <= jhi; ++j) {
                    const float* qv = base + j * 144;
                    float sdot = kv[0]*qv[0] + kv[1]*qv[1] + kv[2]*qv[2]
                               + kv[3]*qv[3] + kv[4]*qv[4] + kv[5]*qv[5];
                    sdot *= 0.4082482904638631f;   // 6^-0.5
                    lg[j - jlo] = sdot;
                    mx = fmaxf(mx, sdot);
                }
                int cnt = jhi - jlo + 1;
                float p[3], ps = 0.f;
                for (int jj = 0; jj < cnt; ++jj) { p[jj] = expf(lg[jj] - mx); ps += p[jj]; }
                float inv = 1.0f / ps;
                #pragma unroll
                for (int d = 0; d < 6; ++d) {
                    float ov = 0.f;
                    for (int jj = 0; jj < cnt; ++jj) ov += p[jj] * base[(jlo + jj) * 144 + 96 + d];
                    ores[it][d] = ov * inv;
                }
            }
        }
        __syncthreads();
        #pragma unroll
        for (int it = 0; it < 2; ++it) {
            int task = tid + it * THREADS;
            if (task < 320) {
                int s = task / 80, r = task % 80, i = r / 8, h = r % 8;
                float* dst = sbuf + (s * 10 + i) * 48 + h * 6;
                #pragma unroll
                for (int d = 0; d < 6; ++d) dst[d] = ores[it][d];
            }
        }
        __syncthreads();

        // ---- proj + residual: 40x48, 240 tasks of 2 rows x 4 cols, K=48 ----
        if (tid < 240) {
            const int og = tid % 12, mg = tid / 12;
            const int o0 = og * 4, m0 = mg * 2;
            const float* orow = sbuf + m0 * 48;
            float acc[2][4] = {};
            for (int k = 0; k < 48; k += 4) {
                float4 a0 = *(const float4*)(orow + k);
                float4 a1 = *(const float4*)(orow + 48 + k);
                #pragma unroll
                for (int kk = 0; kk < 4; ++kk) {
                    float4 w0 = *(const float4*)(pw + (k + kk) * 48 + o0);
                    const float e0 = (&a0.x)[kk], e1 = (&a1.x)[kk];
                    #pragma unroll
                    for (int c = 0; c < 4; ++c) {
                        const float w = (&w0.x)[c];
                        acc[0][c] += e0 * w; acc[1][c] += e1 * w;
                    }
                }
            }
            #pragma unroll
            for (int r = 0; r < 2; ++r)
                #pragma unroll
                for (int c = 0; c < 4; ++c)
                    tbuf[(m0 + r) * 48 + o0 + c] += acc[r][c] + pb[o0 + c];
        }
        __syncthreads();

        // ---- ff1 + gelu: 40x192, 240 tasks of 2 rows x 16 cols, K=48 ----
        if (tid < 240) {
            const int og = tid % 12, mg = tid / 12;
            const int o0 = og * 16, m0 = mg * 2;
            const float* trow = tbuf + m0 * 48;
            float acc[2][16] = {};
            for (int k = 0; k < 48; k += 4) {
                float4 a0 = *(const float4*)(trow + k);
                float4 a1 = *(const float4*)(trow + 48 + k);
                #pragma unroll
                for (int kk = 0; kk < 4; ++kk) {
                    const float* wr = f1w + (k + kk) * 192 + o0;
                    float wv[16];
                    *(float4*)(wv)      = *(const float4*)(wr);
                    *(float4*)(wv + 4)  = *(const float4*)(wr + 4);
                    *(float4*)(wv + 8)  = *(const float4*)(wr + 8);
                    *(float4*)(wv + 12) = *(const float4*)(wr + 12);
                    const float e0 = (&a0.x)[kk], e1 = (&a1.x)[kk];
                    #pragma unroll
                    for (int c = 0; c < 16; ++c) {
                        acc[0][c] += e0 * wv[c]; acc[1][c] += e1 * wv[c];
                    }
                }
            }
            #pragma unroll
            for (int r = 0; r < 2; ++r)
                #pragma unroll
                for (int c = 0; c < 16; ++c) {
                    float v = acc[r][c] + f1b[o0 + c];
                    v = 0.5f * v * (1.f + erff(v * 0.70710678118654752f));
                    sbuf[(m0 + r) * 192 + o0 + c] = v;
                }
        }
        __syncthreads();

        // ---- ff2 + residual: 40x48, 240 tasks of 2 rows x 4 cols, K=192 ----
        if (tid < 240) {
            const int og = tid % 12, mg = tid / 12;
            const int o0 = og * 4, m0 = mg * 2;
            const float* hrow = sbuf + m0 * 192;
            float acc[2][4] = {};
            for (int k = 0; k < 192; k += 4) {
                float4 a0 = *(const float4*)(hrow + k);
                float4 a1 = *(const float4*)(hrow + 192 + k);
                #pragma unroll
                for (int kk = 0; kk < 4; ++kk) {
                    float4 w0 = *(const float4*)(f2w + (k + kk) * 48 + o0);
                    const float e0 = (&a0.x)[kk], e1 = (&a1.x)[kk];
                    #pragma unroll
                    for (int c = 0; c < 4; ++c) {
                        const float w = (&w0.x)[c];
                        acc[0][c] += e0 * w; acc[1][c] += e1 * w;
                    }
                }
            }
            #pragma unroll
            for (int r = 0; r < 2; ++r)
                #pragma unroll
                for (int c = 0; c < 4; ++c)
                    tbuf[(m0 + r) * 48 + o0 + c] += acc[r][c] + f2b[o0 + c];
        }
        __syncthreads();
    }

    // store: t_out pixel-major; block's 1920 floats are contiguous
    {
        float* dst = t_out + ((size_t)(b * 4096 + hw0)) * 480;
        for (int q = tid; q < 480; q += THREADS)
            *(float4*)(dst + q * 4) = *(const float4*)(tbuf + q * 4);
    }
}

// ---------------- Kernel B: depthwise 3x3 conv (SAME) + transpose to pixel-major ----------------
__global__ __launch_bounds__(THREADS) void kb_conv(
    const float* __restrict__ x, const float* __restrict__ t_in,
    const float* __restrict__ dw_w, const float* __restrict__ dw_b,
    float* __restrict__ z0)
{
    __shared__ float ct[100 * 97];     // 10x10 halo tile x 96 ch, stride 97 (bank pad)
    const int tid = threadIdx.x;
    const int blk = blockIdx.x;
    const int n = blk >> 6;            // image (b*10+c)
    const int tile = blk & 63;
    const int th0 = (tile >> 3) << 3;
    const int tw0 = (tile & 7) << 3;
    const int b = n / 10, c = n % 10;

    // x half of cat: channels 0..47, planar layout
    for (int idx = tid; idx < 4800; idx += THREADS) {
        int f = idx / 100, p = idx % 100;
        int py = p / 10, px = p % 10;
        int gh = th0 + py - 1, gw = tw0 + px - 1;
        float v = 0.f;
        if ((unsigned)gh < 64u && (unsigned)gw < 64u)
            v = x[((size_t)n * 48 + f) * 4096 + gh * 64 + gw];
        ct[p * 97 + f] = v;
    }
    // y half of cat: channels 48..95, from t (pixel-major)
    for (int idx = tid; idx < 4800; idx += THREADS) {
        int p = idx / 48, f = idx % 48;
        int py = p / 10, px = p % 10;
        int gh = th0 + py - 1, gw = tw0 + px - 1;
        float v = 0.f;
        if ((unsigned)gh < 64u && (unsigned)gw < 64u)
            v = t_in[(size_t)(b * 4096 + gh * 64 + gw) * 480 + c * 48 + f];
        ct[p * 97 + 48 + f] = v;
    }
    __syncthreads();

    #pragma unroll 4
    for (int it = 0; it < 24; ++it) {
        int oidx = tid + it * THREADS;   // 24*256 == 6144 == 64px * 96ch
        int pxl = oidx / 96, ch = oidx % 96;
        int py = pxl >> 3, pxx = pxl & 7;
        const float* wp = dw_w + ch * 9;
        float acc = dw_b[ch];
        #pragma unroll
        for (int dy = 0; dy < 3; ++dy)
            #pragma unroll
            for (int dx = 0; dx < 3; ++dx)
                acc += ct[((py + dy) * 10 + pxx + dx) * 97 + ch] * wp[dy * 3 + dx];
        z0[((size_t)n * 4096 + (th0 + py) * 64 + (tw0 + pxx)) * 96 + ch] = acc;
    }
}

// ---------------- Kernel C: LN + pw1+gelu+pw2 + shortcut, cooperative 64px/block ----------------
// LDS: zb 25.6KB + hb 25.6KB = 51.2KB -> 3 blocks/CU
__global__ __launch_bounds__(THREADS, 3) void kc_mlp(
    const float* __restrict__ x, const float* __restrict__ t_in,
    const float* __restrict__ z0,
    const float* __restrict__ ln_g, const float* __restrict__ ln_b,
    const float* __restrict__ pw1_w, const float* __restrict__ pw1_b,
    const float* __restrict__ pw2_w, const float* __restrict__ pw2_b,
    const float* __restrict__ sc_w, const float* __restrict__ sc_b,
    float* __restrict__ out)
{
    __shared__ float zb[64 * 100];   // z rows (stride 100, 16B aligned); later: cat rows
    __shared__ float hb[64 * 100];   // h chunk rows (stride 100); later: out staging [f*66+px]
    const int tid = threadIdx.x;
    const int blk = blockIdx.x;       // 5120
    const int n   = blk >> 6;         // image 0..79
    const int hw0 = (blk & 63) << 6;  // 64-pixel run
    const size_t pixbase = (size_t)n * 4096 + hw0;

    // ---- stage z0 (contiguous 6144 floats) ----
    for (int idx = tid; idx < 1536; idx += THREADS) {
        float4 v = *(const float4*)(z0 + pixbase * 96 + (size_t)idx * 4);
        int p = idx / 24, c0 = (idx % 24) * 4;
        *(float4*)(&zb[p * 100 + c0]) = v;
    }
    __syncthreads();

    // ---- LayerNorm in place: one lane per pixel ----
    if (tid < 64) {
        float* r = zb + tid * 100;
        float mu = 0.f;
        #pragma unroll
        for (int k = 0; k < 96; ++k) mu += r[k];
        mu *= (1.f / 96.f);
        float var = 0.f;
        #pragma unroll
        for (int k = 0; k < 96; ++k) { float d = r[k] - mu; var += d * d; }
        var *= (1.f / 96.f);
        float rs = rsqrtf(var + 1e-6f);
        #pragma unroll
        for (int k = 0; k < 96; ++k) r[k] = (r[k] - mu) * rs * ln_g[k] + ln_b[k];
    }
    __syncthreads();

    const int pxg = tid >> 3;          // 0..31 (2 pixels each)
    const int sub = tid & 7;           // 8 col-groups
    const int f0  = sub * 6;           // phase3/shortcut cols (6 each, 48 total)

    float facc[2][6];
    #pragma unroll
    for (int r = 0; r < 2; ++r)
        #pragma unroll
        for (int c = 0; c < 6; ++c) facc[r][c] = pw2_b[f0 + c];

    for (int jc = 0; jc < 4; ++jc) {
        // ---- phase2: h = gelu(z @ pw1[:, jc*96+...] + b), 2px x 12j per thread ----
        {
            const int j0 = jc * 96 + sub * 12;
            const float* zr = zb + pxg * 200;
            float h[2][12] = {};
            for (int k = 0; k < 96; k += 4) {
                float4 a0 = *(const float4*)(zr + k);
                float4 a1 = *(const float4*)(zr + 100 + k);
                #pragma unroll
                for (int kk = 0; kk < 4; ++kk) {
                    const float* wr = pw1_w + (k + kk) * 384 + j0;
                    float wv[12];
                    *(float4*)(wv)     = *(const float4*)(wr);
                    *(float4*)(wv + 4) = *(const float4*)(wr + 4);
                    *(float4*)(wv + 8) = *(const float4*)(wr + 8);
                    const float e0 = (&a0.x)[kk], e1 = (&a1.x)[kk];
                    #pragma unroll
                    for (int c = 0; c < 12; ++c) {
                        h[0][c] += e0 * wv[c]; h[1][c] += e1 * wv[c];
                    }
                }
            }
            #pragma unroll
            for (int r = 0; r < 2; ++r)
                #pragma unroll
                for (int c = 0; c < 12; ++c) {
                    float v = h[r][c] + pw1_b[j0 + c];
                    v = 0.5f * v * (1.f + erff(v * 0.70710678118654752f));
                    hb[(pxg * 2 + r) * 100 + sub * 12 + c] = v;
                }
        }
        __syncthreads();

        // ---- phase3: facc += h_chunk @ pw2[jc*96+..., :], 2px x 6f per thread ----
        {
            const float* hr = hb + pxg * 200;
            for (int k = 0; k < 96; k += 4) {
                float4 a0 = *(const float4*)(hr + k);
                float4 a1 = *(const float4*)(hr + 100 + k);
                #pragma unroll
                for (int kk = 0; kk < 4; ++kk) {
                    const float* wr = pw2_w + (jc * 96 + k + kk) * 48 + f0;
                    const float e0 = (&a0.x)[kk], e1 = (&a1.x)[kk];
                    #pragma unroll
                    for (int c = 0; c < 6; ++c) {
                        const float w = wr[c];
                        facc[0][c] += e0 * w; facc[1][c] += e1 * w;
                    }
                }
            }
        }
        __syncthreads();   // hb reused by next chunk; zb re-read
    }

    // ---- stage cat (x planar ch 0..47, t pixel-major ch 48..95) into zb ----
    for (int idx = tid; idx < 768; idx += THREADS) {
        int ch = idx >> 4, p0 = (idx & 15) << 2;
        float4 v = *(const float4*)(x + ((size_t)n * 48 + ch) * 4096 + hw0 + p0);
        zb[(p0 + 0) * 100 + ch] = v.x; zb[(p0 + 1) * 100 + ch] = v.y;
        zb[(p0 + 2) * 100 + ch] = v.z; zb[(p0 + 3) * 100 + ch] = v.w;
    }
    {
        const size_t tb = ((size_t)(n / 10) * 4096 + hw0);
        const int coff = (n % 10) * 48;
        for (int idx = tid; idx < 768; idx += THREADS) {
            int p = idx / 12, u0 = (idx % 12) * 4;
            float4 v = *(const float4*)(t_in + (tb + p) * 480 + coff + u0);
            *(float4*)(&zb[p * 100 + 48 + u0]) = v;
        }
    }
    __syncthreads();

    // ---- shortcut: facc += cat @ sc_w^T (sc_w is [48 out][96 in]), aligned f4 rows ----
    {
        const float* cr = zb + pxg * 200;
        for (int k = 0; k < 96; k += 4) {
            float4 a0 = *(const float4*)(cr + k);
            float4 a1 = *(const float4*)(cr + 100 + k);
            float4 w[6];
            #pragma unroll
            for (int c = 0; c < 6; ++c)
                w[c] = *(const float4*)(sc_w + (f0 + c) * 96 + k);
            #pragma unroll
            for (int kk = 0; kk < 4; ++kk) {
                const float e0 = (&a0.x)[kk], e1 = (&a1.x)[kk];
                #pragma unroll
                for (int c = 0; c < 6; ++c) {
                    const float q = (&w[c].x)[kk];
                    facc[0][c] += e0 * q; facc[1][c] += e1 * q;
                }
            }
        }
    }
    __syncthreads();   // zb/hb done; reuse hb for output staging

    // ---- epilogue: stage [f][px] (stride 66), then coalesced float4 stores ----
    #pragma unroll
    for (int r = 0; r < 2; ++r)
        #pragma unroll
        for (int c = 0; c < 6; ++c)
            hb[(f0 + c) * 66 + pxg * 2 + r] = facc[r][c] + sc_b[f0 + c];
    __syncthreads();
    for (int idx = tid; idx < 768; idx += THREADS) {
        int f = idx / 16, p0 = (idx % 16) * 4;
        float4 v;
        v.x = hb[f * 66 + p0]; v.y = hb[f * 66 + p0 + 1];
        v.z = hb[f * 66 + p0 + 2]; v.w = hb[f * 66 + p0 + 3];
        *(float4*)(out + ((size_t)n * 48 + f) * 4096 + hw0 + p0) = v;
    }
}

extern "C" void kernel_launch(void* const* d_in, const int* in_sizes, int n_in,
                              void* d_out, int out_size, void* d_ws, size_t ws_size,
                              hipStream_t stream) {
    const float* x      = (const float*)d_in[0];
    const float* qkv_w  = (const float*)d_in[1];
    const float* qkv_b  = (const float*)d_in[2];
    const float* proj_w = (const float*)d_in[3];
    const float* proj_b = (const float*)d_in[4];
    const float* ff1_w  = (const float*)d_in[5];
    const float* ff1_b  = (const float*)d_in[6];
    const float* ff2_w  = (const float*)d_in[7];
    const float* ff2_b  = (const float*)d_in[8];
    const float* dw_w   = (const float*)d_in[9];
    const float* dw_b   = (const float*)d_in[10];
    const float* ln_g   = (const float*)d_in[11];
    const float* ln_b   = (const float*)d_in[12];
    const float* pw1_w  = (const float*)d_in[13];
    const float* pw1_b  = (const float*)d_in[14];
    const float* pw2_w  = (const float*)d_in[15];
    const float* pw2_b  = (const float*)d_in[16];
    const float* sc_w   = (const float*)d_in[17];
    const float* sc_b   = (const float*)d_in[18];
    float* out = (float*)d_out;

    // workspace: t_final (B*H*W,10,48) = 15,728,640 f ; z0 (80*4096,96) = 31,457,280 f
    float* t_out = (float*)d_ws;
    float* z0    = t_out + 15728640ull;

    ka_transformer<<<8192, THREADS, 0, stream>>>(x, qkv_w, qkv_b, proj_w, proj_b,
                                                 ff1_w, ff1_b, ff2_w, ff2_b, t_out);
    kb_conv<<<5120, THREADS, 0, stream>>>(x, t_out, dw_w, dw_b, z0);
    kc_mlp<<<5120, THREADS, 0, stream>>>(x, t_out, z0, ln_g, ln_b,
                                         pw1_w, pw1_b, pw2_w, pw2_b, sc_w, sc_b, out);
}

// Round 4
// 3273.742 us; speedup vs baseline: 1.0111x; 1.0111x over previous
//
#include <hip/hip_runtime.h>
#include <math.h>

#define THREADS 256

// Dims: B=8, C(seq)=10, F(dim)=48, H=W=64, HEADS=8, hd=6, MLP=192
// Stage2: NI=80 images, CH=96, PW=384, OUTF=48
//
// CRITICAL: no address-taken locals anywhere ((&v.x)[i] / *(float4*)local
// defeats SROA -> scratch spills -> ~450MB/dispatch HBM traffic, seen R2/R3).
// All register tiles are constant-indexed arrays + named float4 components.

#define FMA4(A, e, w0) \
    A[0] += (e)*(w0).x; A[1] += (e)*(w0).y; A[2] += (e)*(w0).z; A[3] += (e)*(w0).w;
#define FMA12(A, e, w0, w1, w2) \
    A[0] += (e)*(w0).x; A[1] += (e)*(w0).y; A[2]  += (e)*(w0).z; A[3]  += (e)*(w0).w; \
    A[4] += (e)*(w1).x; A[5] += (e)*(w1).y; A[6]  += (e)*(w1).z; A[7]  += (e)*(w1).w; \
    A[8] += (e)*(w2).x; A[9] += (e)*(w2).y; A[10] += (e)*(w2).z; A[11] += (e)*(w2).w;
#define FMA16(A, e, w0, w1, w2, w3) \
    FMA12(A, e, w0, w1, w2) \
    A[12] += (e)*(w3).x; A[13] += (e)*(w3).y; A[14] += (e)*(w3).z; A[15] += (e)*(w3).w;
#define FMA6S(A, e, b0, b1, b2, b3, b4, b5) \
    A[0] += (e)*(b0); A[1] += (e)*(b1); A[2] += (e)*(b2); \
    A[3] += (e)*(b3); A[4] += (e)*(b4); A[5] += (e)*(b5);

// Token-row stride in LDS: 52 floats (2-way bank aliasing only; 16B aligned)
#define TS 52
// h1-row stride: 196 floats
#define HS 196

// ---------------- Kernel A: fused 2-layer transformer, 4 sequences/block ----------------
// LDS: tbuf 40*52*4=8.3KB + sbuf 7840*4=31.4KB = 39.7KB -> 4 blocks/CU
__global__ __launch_bounds__(THREADS, 4) void ka_transformer(
    const float* __restrict__ x,
    const float* __restrict__ qkv_w, const float* __restrict__ qkv_b,
    const float* __restrict__ proj_w, const float* __restrict__ proj_b,
    const float* __restrict__ ff1_w, const float* __restrict__ ff1_b,
    const float* __restrict__ ff2_w, const float* __restrict__ ff2_b,
    float* __restrict__ t_out)
{
    __shared__ float tbuf[40 * TS];   // token m=s*10+c at m*TS, 48 floats each
    __shared__ float sbuf[7840];      // qkv: m*144+o ; attn-out: m*TS ; h1: m*HS
    const int tid = threadIdx.x;
    const int blk = blockIdx.x;          // 8192 blocks
    const int b   = blk & 7;             // XCD-aligned image (round-robin dispatch)
    const int hw0 = (blk >> 3) << 2;     // 4 pixels per block, contiguous per XCD

    // stage: x[(b*480+cf)*4096 + hw0 + s] -> tbuf[(s*10+c)*TS + f]
    for (int cf = tid; cf < 480; cf += THREADS) {
        const int c = cf / 48, f = cf % 48;
        const float4 v = *(const float4*)(x + ((size_t)(b * 480 + cf)) * 4096 + hw0);
        tbuf[c * TS + f]        = v.x;
        tbuf[(10 + c) * TS + f] = v.y;
        tbuf[(20 + c) * TS + f] = v.z;
        tbuf[(30 + c) * TS + f] = v.w;
    }
    __syncthreads();

    for (int l = 0; l < 2; ++l) {
        const float* qw  = qkv_w + l * 6912;
        const float* qb  = qkv_b + l * 144;
        const float* pw  = proj_w + l * 2304;
        const float* pb  = proj_b + l * 48;
        const float* f1w = ff1_w + l * 9216;
        const float* f1b = ff1_b + l * 192;
        const float* f2w = ff2_w + l * 9216;
        const float* f2b = ff2_b + l * 48;

        // ---- qkv: 40x144, 240 tasks of 2 rows x 12 cols, K=48 ----
        if (tid < 240) {
            const int og = tid % 12, mg = tid / 12;
            const int o0 = og * 12, m0 = mg * 2;
            const float* trow = tbuf + m0 * TS;
            float acc0[12] = {0,0,0,0,0,0,0,0,0,0,0,0};
            float acc1[12] = {0,0,0,0,0,0,0,0,0,0,0,0};
            for (int k = 0; k < 48; k += 4) {
                const float4 a0 = *(const float4*)(trow + k);
                const float4 a1 = *(const float4*)(trow + TS + k);
#define QSTEP(comp, kk) { \
                const float* wr = qw + (k + kk) * 144 + o0; \
                const float4 w0 = *(const float4*)wr; \
                const float4 w1 = *(const float4*)(wr + 4); \
                const float4 w2 = *(const float4*)(wr + 8); \
                FMA12(acc0, a0.comp, w0, w1, w2) \
                FMA12(acc1, a1.comp, w0, w1, w2) }
                QSTEP(x, 0) QSTEP(y, 1) QSTEP(z, 2) QSTEP(w, 3)
#undef QSTEP
            }
            #pragma unroll
            for (int c = 0; c < 12; ++c) {
                const float bb = qb[o0 + c];
                sbuf[m0 * 144 + o0 + c]       = acc0[c] + bb;
                sbuf[(m0 + 1) * 144 + o0 + c] = acc1[c] + bb;
            }
        }
        __syncthreads();

        // ---- banded attention: 4 seq x 10 i x 8 h = 320 tasks, branch-free band ----
        float ores[2][6];
        #pragma unroll
        for (int it = 0; it < 2; ++it) {
            const int task = tid + it * THREADS;
            if (task < 320) {
                const int s = task / 80, r = task % 80, i = r / 8, h = r % 8;
                const float* base = sbuf + s * 1440 + h * 6;
                const float* ki = base + i * 144 + 48;
                const float k0 = ki[0], k1 = ki[1], k2 = ki[2], k3 = ki[3], k4 = ki[4], k5 = ki[5];
                const int jm = (i > 0) ? i - 1 : 0;
                const int jp = (i < 9) ? i + 1 : 9;
                const float* qm = base + jm * 144;
                const float* qc = base + i * 144;
                const float* qp = base + jp * 144;
                const float sc = 0.4082482904638631f;  // 6^-0.5
                float s0 = (k0*qm[0]+k1*qm[1]+k2*qm[2]+k3*qm[3]+k4*qm[4]+k5*qm[5]) * sc;
                float s1 = (k0*qc[0]+k1*qc[1]+k2*qc[2]+k3*qc[3]+k4*qc[4]+k5*qc[5]) * sc;
                float s2 = (k0*qp[0]+k1*qp[1]+k2*qp[2]+k3*qp[3]+k4*qp[4]+k5*qp[5]) * sc;
                if (i == 0) s0 = -3.4e38f;
                if (i == 9) s2 = -3.4e38f;
                const float mx = fmaxf(s0, fmaxf(s1, s2));
                const float p0 = expf(s0 - mx), p1 = expf(s1 - mx), p2 = expf(s2 - mx);
                const float inv = 1.0f / (p0 + p1 + p2);
                const float* vm = qm + 96;
                const float* vc = qc + 96;
                const float* vp = qp + 96;
                #pragma unroll
                for (int d = 0; d < 6; ++d)
                    ores[it][d] = (p0 * vm[d] + p1 * vc[d] + p2 * vp[d]) * inv;
            }
        }
        __syncthreads();
        #pragma unroll
        for (int it = 0; it < 2; ++it) {
            const int task = tid + it * THREADS;
            if (task < 320) {
                const int s = task / 80, r = task % 80, i = r / 8, h = r % 8;
                float* dst = sbuf + (s * 10 + i) * TS + h * 6;
                #pragma unroll
                for (int d = 0; d < 6; ++d) dst[d] = ores[it][d];
            }
        }
        __syncthreads();

        // ---- proj + residual: 40x48, 240 tasks of 2 rows x 4 cols, K=48 ----
        if (tid < 240) {
            const int og = tid % 12, mg = tid / 12;
            const int o0 = og * 4, m0 = mg * 2;
            const float* orow = sbuf + m0 * TS;
            float acc0[4] = {0,0,0,0};
            float acc1[4] = {0,0,0,0};
            for (int k = 0; k < 48; k += 4) {
                const float4 a0 = *(const float4*)(orow + k);
                const float4 a1 = *(const float4*)(orow + TS + k);
#define PSTEP(comp, kk) { \
                const float4 w0 = *(const float4*)(pw + (k + kk) * 48 + o0); \
                FMA4(acc0, a0.comp, w0) \
                FMA4(acc1, a1.comp, w0) }
                PSTEP(x, 0) PSTEP(y, 1) PSTEP(z, 2) PSTEP(w, 3)
#undef PSTEP
            }
            #pragma unroll
            for (int c = 0; c < 4; ++c) {
                const float bb = pb[o0 + c];
                tbuf[m0 * TS + o0 + c]       += acc0[c] + bb;
                tbuf[(m0 + 1) * TS + o0 + c] += acc1[c] + bb;
            }
        }
        __syncthreads();

        // ---- ff1 + gelu: 40x192, 240 tasks of 2 rows x 16 cols, K=48 ----
        if (tid < 240) {
            const int og = tid % 12, mg = tid / 12;
            const int o0 = og * 16, m0 = mg * 2;
            const float* trow = tbuf + m0 * TS;
            float acc0[16] = {0,0,0,0,0,0,0,0,0,0,0,0,0,0,0,0};
            float acc1[16] = {0,0,0,0,0,0,0,0,0,0,0,0,0,0,0,0};
            for (int k = 0; k < 48; k += 4) {
                const float4 a0 = *(const float4*)(trow + k);
                const float4 a1 = *(const float4*)(trow + TS + k);
#define FSTEP(comp, kk) { \
                const float* wr = f1w + (k + kk) * 192 + o0; \
                const float4 w0 = *(const float4*)wr; \
                const float4 w1 = *(const float4*)(wr + 4); \
                const float4 w2 = *(const float4*)(wr + 8); \
                const float4 w3 = *(const float4*)(wr + 12); \
                FMA16(acc0, a0.comp, w0, w1, w2, w3) \
                FMA16(acc1, a1.comp, w0, w1, w2, w3) }
                FSTEP(x, 0) FSTEP(y, 1) FSTEP(z, 2) FSTEP(w, 3)
#undef FSTEP
            }
            #pragma unroll
            for (int c = 0; c < 16; ++c) {
                float v0 = acc0[c] + f1b[o0 + c];
                float v1 = acc1[c] + f1b[o0 + c];
                v0 = 0.5f * v0 * (1.f + erff(v0 * 0.70710678118654752f));
                v1 = 0.5f * v1 * (1.f + erff(v1 * 0.70710678118654752f));
                sbuf[m0 * HS + o0 + c]       = v0;
                sbuf[(m0 + 1) * HS + o0 + c] = v1;
            }
        }
        __syncthreads();

        // ---- ff2 + residual: 40x48, 240 tasks of 2 rows x 4 cols, K=192 ----
        if (tid < 240) {
            const int og = tid % 12, mg = tid / 12;
            const int o0 = og * 4, m0 = mg * 2;
            const float* hrow = sbuf + m0 * HS;
            float acc0[4] = {0,0,0,0};
            float acc1[4] = {0,0,0,0};
            for (int k = 0; k < 192; k += 4) {
                const float4 a0 = *(const float4*)(hrow + k);
                const float4 a1 = *(const float4*)(hrow + HS + k);
#define GSTEP(comp, kk) { \
                const float4 w0 = *(const float4*)(f2w + (k + kk) * 48 + o0); \
                FMA4(acc0, a0.comp, w0) \
                FMA4(acc1, a1.comp, w0) }
                GSTEP(x, 0) GSTEP(y, 1) GSTEP(z, 2) GSTEP(w, 3)
#undef GSTEP
            }
            #pragma unroll
            for (int c = 0; c < 4; ++c) {
                const float bb = f2b[o0 + c];
                tbuf[m0 * TS + o0 + c]       += acc0[c] + bb;
                tbuf[(m0 + 1) * TS + o0 + c] += acc1[c] + bb;
            }
        }
        __syncthreads();
    }

    // store: t_out[(b*4096+hw0)*480 + m*48 + f] = tbuf[m*TS + f]
    {
        float* dst = t_out + ((size_t)(b * 4096 + hw0)) * 480;
        for (int q = tid; q < 480; q += THREADS) {
            const int m = q / 12, part = (q % 12) * 4;
            *(float4*)(dst + m * 48 + part) = *(const float4*)(tbuf + m * TS + part);
        }
    }
}

// ---------------- Kernel B: depthwise 3x3 conv (SAME) + transpose to pixel-major ----------------
__global__ __launch_bounds__(THREADS) void kb_conv(
    const float* __restrict__ x, const float* __restrict__ t_in,
    const float* __restrict__ dw_w, const float* __restrict__ dw_b,
    float* __restrict__ z0)
{
    __shared__ float ct[100 * 97];     // 10x10 halo tile x 96 ch, stride 97 (bank pad)
    const int tid = threadIdx.x;
    const int blk = blockIdx.x;
    const int n = blk >> 6;            // image (b*10+c)
    const int tile = blk & 63;
    const int th0 = (tile >> 3) << 3;
    const int tw0 = (tile & 7) << 3;
    const int b = n / 10, c = n % 10;

    // x half of cat: channels 0..47, planar layout
    for (int idx = tid; idx < 4800; idx += THREADS) {
        int f = idx / 100, p = idx % 100;
        int py = p / 10, px = p % 10;
        int gh = th0 + py - 1, gw = tw0 + px - 1;
        float v = 0.f;
        if ((unsigned)gh < 64u && (unsigned)gw < 64u)
            v = x[((size_t)n * 48 + f) * 4096 + gh * 64 + gw];
        ct[p * 97 + f] = v;
    }
    // y half of cat: channels 48..95, from t (pixel-major)
    for (int idx = tid; idx < 4800; idx += THREADS) {
        int p = idx / 48, f = idx % 48;
        int py = p / 10, px = p % 10;
        int gh = th0 + py - 1, gw = tw0 + px - 1;
        float v = 0.f;
        if ((unsigned)gh < 64u && (unsigned)gw < 64u)
            v = t_in[(size_t)(b * 4096 + gh * 64 + gw) * 480 + c * 48 + f];
        ct[p * 97 + 48 + f] = v;
    }
    __syncthreads();

    #pragma unroll 4
    for (int it = 0; it < 24; ++it) {
        int oidx = tid + it * THREADS;   // 24*256 == 6144 == 64px * 96ch
        int pxl = oidx / 96, ch = oidx % 96;
        int py = pxl >> 3, pxx = pxl & 7;
        const float* wp = dw_w + ch * 9;
        float acc = dw_b[ch];
        #pragma unroll
        for (int dy = 0; dy < 3; ++dy)
            #pragma unroll
            for (int dx = 0; dx < 3; ++dx)
                acc += ct[((py + dy) * 10 + pxx + dx) * 97 + ch] * wp[dy * 3 + dx];
        z0[((size_t)n * 4096 + (th0 + py) * 64 + (tw0 + pxx)) * 96 + ch] = acc;
    }
}

// ---------------- Kernel C: LN + pw1+gelu+pw2 + shortcut, cooperative 64px/block ----------------
// LDS: zb 25.6KB + hb 25.6KB = 51.2KB -> 3 blocks/CU
__global__ __launch_bounds__(THREADS, 3) void kc_mlp(
    const float* __restrict__ x, const float* __restrict__ t_in,
    const float* __restrict__ z0,
    const float* __restrict__ ln_g, const float* __restrict__ ln_b,
    const float* __restrict__ pw1_w, const float* __restrict__ pw1_b,
    const float* __restrict__ pw2_w, const float* __restrict__ pw2_b,
    const float* __restrict__ sc_w, const float* __restrict__ sc_b,
    float* __restrict__ out)
{
    __shared__ float zb[64 * 100];   // z rows (stride 100, 16B aligned); later: cat rows
    __shared__ float hb[64 * 100];   // h chunk rows (stride 100); later: out staging [f*66+px]
    const int tid = threadIdx.x;
    const int blk = blockIdx.x;       // 5120
    const int n   = blk >> 6;         // image 0..79
    const int hw0 = (blk & 63) << 6;  // 64-pixel run
    const size_t pixbase = (size_t)n * 4096 + hw0;

    // ---- stage z0 (contiguous 6144 floats) ----
    for (int idx = tid; idx < 1536; idx += THREADS) {
        float4 v = *(const float4*)(z0 + pixbase * 96 + (size_t)idx * 4);
        int p = idx / 24, c0 = (idx % 24) * 4;
        *(float4*)(&zb[p * 100 + c0]) = v;
    }
    __syncthreads();

    // ---- LayerNorm in place: one lane per pixel ----
    if (tid < 64) {
        float* r = zb + tid * 100;
        float mu = 0.f;
        #pragma unroll
        for (int k = 0; k < 96; ++k) mu += r[k];
        mu *= (1.f / 96.f);
        float var = 0.f;
        #pragma unroll
        for (int k = 0; k < 96; ++k) { float d = r[k] - mu; var += d * d; }
        var *= (1.f / 96.f);
        float rs = rsqrtf(var + 1e-6f);
        #pragma unroll
        for (int k = 0; k < 96; ++k) r[k] = (r[k] - mu) * rs * ln_g[k] + ln_b[k];
    }
    __syncthreads();

    const int pxg = tid >> 3;          // 0..31 (2 pixels each)
    const int sub = tid & 7;           // 8 col-groups
    const int f0  = sub * 6;           // phase3/shortcut cols (6 each, 48 total)

    float fa0[6], fa1[6];
    #pragma unroll
    for (int c = 0; c < 6; ++c) { fa0[c] = pw2_b[f0 + c]; fa1[c] = fa0[c]; }

    for (int jc = 0; jc < 4; ++jc) {
        // ---- phase2: h = gelu(z @ pw1[:, jc*96+...] + b), 2px x 12j per thread ----
        {
            const int j0 = jc * 96 + sub * 12;
            const float* zr = zb + pxg * 200;
            float h0[12] = {0,0,0,0,0,0,0,0,0,0,0,0};
            float h1[12] = {0,0,0,0,0,0,0,0,0,0,0,0};
            for (int k = 0; k < 96; k += 4) {
                const float4 a0 = *(const float4*)(zr + k);
                const float4 a1 = *(const float4*)(zr + 100 + k);
#define HSTEP(comp, kk) { \
                const float* wr = pw1_w + (k + kk) * 384 + j0; \
                const float4 w0 = *(const float4*)wr; \
                const float4 w1 = *(const float4*)(wr + 4); \
                const float4 w2 = *(const float4*)(wr + 8); \
                FMA12(h0, a0.comp, w0, w1, w2) \
                FMA12(h1, a1.comp, w0, w1, w2) }
                HSTEP(x, 0) HSTEP(y, 1) HSTEP(z, 2) HSTEP(w, 3)
#undef HSTEP
            }
            #pragma unroll
            for (int c = 0; c < 12; ++c) {
                float v0 = h0[c] + pw1_b[j0 + c];
                float v1 = h1[c] + pw1_b[j0 + c];
                v0 = 0.5f * v0 * (1.f + erff(v0 * 0.70710678118654752f));
                v1 = 0.5f * v1 * (1.f + erff(v1 * 0.70710678118654752f));
                hb[(pxg * 2) * 100 + sub * 12 + c]     = v0;
                hb[(pxg * 2 + 1) * 100 + sub * 12 + c] = v1;
            }
        }
        __syncthreads();

        // ---- phase3: facc += h_chunk @ pw2[jc*96+..., :], 2px x 6f per thread ----
        {
            const float* hr = hb + pxg * 200;
            for (int k = 0; k < 96; k += 4) {
                const float4 a0 = *(const float4*)(hr + k);
                const float4 a1 = *(const float4*)(hr + 100 + k);
#define P3STEP(comp, kk) { \
                const float* wr = pw2_w + (jc * 96 + k + kk) * 48 + f0; \
                const float b0 = wr[0], b1 = wr[1], b2 = wr[2], b3 = wr[3], b4 = wr[4], b5 = wr[5]; \
                FMA6S(fa0, a0.comp, b0, b1, b2, b3, b4, b5) \
                FMA6S(fa1, a1.comp, b0, b1, b2, b3, b4, b5) }
                P3STEP(x, 0) P3STEP(y, 1) P3STEP(z, 2) P3STEP(w, 3)
#undef P3STEP
            }
        }
        __syncthreads();   // hb reused by next chunk; zb re-read
    }

    // ---- stage cat (x planar ch 0..47, t pixel-major ch 48..95) into zb ----
    for (int idx = tid; idx < 768; idx += THREADS) {
        int ch = idx >> 4, p0 = (idx & 15) << 2;
        float4 v = *(const float4*)(x + ((size_t)n * 48 + ch) * 4096 + hw0 + p0);
        zb[(p0 + 0) * 100 + ch] = v.x; zb[(p0 + 1) * 100 + ch] = v.y;
        zb[(p0 + 2) * 100 + ch] = v.z; zb[(p0 + 3) * 100 + ch] = v.w;
    }
    {
        const size_t tb = ((size_t)(n / 10) * 4096 + hw0);
        const int coff = (n % 10) * 48;
        for (int idx = tid; idx < 768; idx += THREADS) {
            int p = idx / 12, u0 = (idx % 12) * 4;
            float4 v = *(const float4*)(t_in + (tb + p) * 480 + coff + u0);
            *(float4*)(&zb[p * 100 + 48 + u0]) = v;
        }
    }
    __syncthreads();

    // ---- shortcut: facc += cat @ sc_w^T (sc_w is [48 out][96 in]) ----
    {
        const float* cr = zb + pxg * 200;
        for (int k = 0; k < 96; k += 4) {
            const float4 a0 = *(const float4*)(cr + k);
            const float4 a1 = *(const float4*)(cr + 100 + k);
            const float4 wA = *(const float4*)(sc_w + (f0 + 0) * 96 + k);
            const float4 wB = *(const float4*)(sc_w + (f0 + 1) * 96 + k);
            const float4 wC = *(const float4*)(sc_w + (f0 + 2) * 96 + k);
            const float4 wD = *(const float4*)(sc_w + (f0 + 3) * 96 + k);
            const float4 wE = *(const float4*)(sc_w + (f0 + 4) * 96 + k);
            const float4 wF = *(const float4*)(sc_w + (f0 + 5) * 96 + k);
#define SCSTEP(comp) \
            FMA6S(fa0, a0.comp, wA.comp, wB.comp, wC.comp, wD.comp, wE.comp, wF.comp) \
            FMA6S(fa1, a1.comp, wA.comp, wB.comp, wC.comp, wD.comp, wE.comp, wF.comp)
            SCSTEP(x) SCSTEP(y) SCSTEP(z) SCSTEP(w)
#undef SCSTEP
        }
    }
    __syncthreads();   // zb/hb done; reuse hb for output staging

    // ---- epilogue: stage [f][px] (stride 66), then coalesced float4 stores ----
    #pragma unroll
    for (int c = 0; c < 6; ++c) {
        hb[(f0 + c) * 66 + pxg * 2]     = fa0[c] + sc_b[f0 + c];
        hb[(f0 + c) * 66 + pxg * 2 + 1] = fa1[c] + sc_b[f0 + c];
    }
    __syncthreads();
    for (int idx = tid; idx < 768; idx += THREADS) {
        int f = idx / 16, p0 = (idx % 16) * 4;
        float4 v;
        v.x = hb[f * 66 + p0]; v.y = hb[f * 66 + p0 + 1];
        v.z = hb[f * 66 + p0 + 2]; v.w = hb[f * 66 + p0 + 3];
        *(float4*)(out + ((size_t)n * 48 + f) * 4096 + hw0 + p0) = v;
    }
}

extern "C" void kernel_launch(void* const* d_in, const int* in_sizes, int n_in,
                              void* d_out, int out_size, void* d_ws, size_t ws_size,
                              hipStream_t stream) {
    const float* x      = (const float*)d_in[0];
    const float* qkv_w  = (const float*)d_in[1];
    const float* qkv_b  = (const float*)d_in[2];
    const float* proj_w = (const float*)d_in[3];
    const float* proj_b = (const float*)d_in[4];
    const float* ff1_w  = (const float*)d_in[5];
    const float* ff1_b  = (const float*)d_in[6];
    const float* ff2_w  = (const float*)d_in[7];
    const float* ff2_b  = (const float*)d_in[8];
    const float* dw_w   = (const float*)d_in[9];
    const float* dw_b   = (const float*)d_in[10];
    const float* ln_g   = (const float*)d_in[11];
    const float* ln_b   = (const float*)d_in[12];
    const float* pw1_w  = (const float*)d_in[13];
    const float* pw1_b  = (const float*)d_in[14];
    const float* pw2_w  = (const float*)d_in[15];
    const float* pw2_b  = (const float*)d_in[16];
    const float* sc_w   = (const float*)d_in[17];
    const float* sc_b   = (const float*)d_in[18];
    float* out = (float*)d_out;

    // workspace: t_final (B*H*W,10,48) = 15,728,640 f ; z0 (80*4096,96) = 31,457,280 f
    float* t_out = (float*)d_ws;
    float* z0    = t_out + 15728640ull;

    ka_transformer<<<8192, THREADS, 0, stream>>>(x, qkv_w, qkv_b, proj_w, proj_b,
                                                 ff1_w, ff1_b, ff2_w, ff2_b, t_out);
    kb_conv<<<5120, THREADS, 0, stream>>>(x, t_out, dw_w, dw_b, z0);
    kc_mlp<<<5120, THREADS, 0, stream>>>(x, t_out, z0, ln_g, ln_b,
                                         pw1_w, pw1_b, pw2_w, pw2_b, sc_w, sc_b, out);
}

// Round 5
// 3137.800 us; speedup vs baseline: 1.0549x; 1.0433x over previous
//
#include <hip/hip_runtime.h>
#include <math.h>

#define THREADS 256

// Dims: B=8, C(seq)=10, F(dim)=48, H=W=64, HEADS=8, hd=6, MLP=192
// Stage2: NI=80 images, CH=96, PW=384, OUTF=48
//
// LESSON (R2-R4): __launch_bounds__(256, k) with k>=3 caps VGPRs at 64 on this
// compiler -> register tiles spill to scratch -> ~400MB/dispatch HBM churn
// (WRITE_SIZE 397MB vs 63MB ideal, VGPR_Count==64). Use plain
// __launch_bounds__(THREADS) and let the allocator pick (R1: 88 VGPR, no spill).

#define FMA4(A, e, w0) \
    A[0] += (e)*(w0).x; A[1] += (e)*(w0).y; A[2] += (e)*(w0).z; A[3] += (e)*(w0).w;
#define FMA12(A, e, w0, w1, w2) \
    A[0] += (e)*(w0).x; A[1] += (e)*(w0).y; A[2]  += (e)*(w0).z; A[3]  += (e)*(w0).w; \
    A[4] += (e)*(w1).x; A[5] += (e)*(w1).y; A[6]  += (e)*(w1).z; A[7]  += (e)*(w1).w; \
    A[8] += (e)*(w2).x; A[9] += (e)*(w2).y; A[10] += (e)*(w2).z; A[11] += (e)*(w2).w;
#define FMA16(A, e, w0, w1, w2, w3) \
    FMA12(A, e, w0, w1, w2) \
    A[12] += (e)*(w3).x; A[13] += (e)*(w3).y; A[14] += (e)*(w3).z; A[15] += (e)*(w3).w;
#define FMA6S(A, e, b0, b1, b2, b3, b4, b5) \
    A[0] += (e)*(b0); A[1] += (e)*(b1); A[2] += (e)*(b2); \
    A[3] += (e)*(b3); A[4] += (e)*(b4); A[5] += (e)*(b5);

// Token-row stride in LDS: 52 floats (2-way bank aliasing only; 16B aligned)
#define TS 52
// h1-row stride: 196 floats
#define HS 196

// ---------------- Kernel A: fused 2-layer transformer, 4 sequences/block ----------------
// LDS: tbuf 40*52*4=8.3KB + sbuf 7840*4=31.4KB = 39.7KB -> up to 4 blocks/CU
__global__ __launch_bounds__(THREADS) void ka_transformer(
    const float* __restrict__ x,
    const float* __restrict__ qkv_w, const float* __restrict__ qkv_b,
    const float* __restrict__ proj_w, const float* __restrict__ proj_b,
    const float* __restrict__ ff1_w, const float* __restrict__ ff1_b,
    const float* __restrict__ ff2_w, const float* __restrict__ ff2_b,
    float* __restrict__ t_out)
{
    __shared__ float tbuf[40 * TS];   // token m=s*10+c at m*TS, 48 floats each
    __shared__ float sbuf[7840];      // qkv: m*144+o ; attn-out: m*TS ; h1: m*HS
    const int tid = threadIdx.x;
    const int blk = blockIdx.x;          // 8192 blocks
    const int b   = blk & 7;             // XCD-aligned image (round-robin dispatch)
    const int hw0 = (blk >> 3) << 2;     // 4 pixels per block, contiguous per XCD

    // stage: x[(b*480+cf)*4096 + hw0 + s] -> tbuf[(s*10+c)*TS + f]
    for (int cf = tid; cf < 480; cf += THREADS) {
        const int c = cf / 48, f = cf % 48;
        const float4 v = *(const float4*)(x + ((size_t)(b * 480 + cf)) * 4096 + hw0);
        tbuf[c * TS + f]        = v.x;
        tbuf[(10 + c) * TS + f] = v.y;
        tbuf[(20 + c) * TS + f] = v.z;
        tbuf[(30 + c) * TS + f] = v.w;
    }
    __syncthreads();

    for (int l = 0; l < 2; ++l) {
        const float* qw  = qkv_w + l * 6912;
        const float* qb  = qkv_b + l * 144;
        const float* pw  = proj_w + l * 2304;
        const float* pb  = proj_b + l * 48;
        const float* f1w = ff1_w + l * 9216;
        const float* f1b = ff1_b + l * 192;
        const float* f2w = ff2_w + l * 9216;
        const float* f2b = ff2_b + l * 48;

        // ---- qkv: 40x144, 240 tasks of 2 rows x 12 cols, K=48 ----
        if (tid < 240) {
            const int og = tid % 12, mg = tid / 12;
            const int o0 = og * 12, m0 = mg * 2;
            const float* trow = tbuf + m0 * TS;
            float acc0[12] = {0,0,0,0,0,0,0,0,0,0,0,0};
            float acc1[12] = {0,0,0,0,0,0,0,0,0,0,0,0};
            for (int k = 0; k < 48; k += 4) {
                const float4 a0 = *(const float4*)(trow + k);
                const float4 a1 = *(const float4*)(trow + TS + k);
#define QSTEP(comp, kk) { \
                const float* wr = qw + (k + kk) * 144 + o0; \
                const float4 w0 = *(const float4*)wr; \
                const float4 w1 = *(const float4*)(wr + 4); \
                const float4 w2 = *(const float4*)(wr + 8); \
                FMA12(acc0, a0.comp, w0, w1, w2) \
                FMA12(acc1, a1.comp, w0, w1, w2) }
                QSTEP(x, 0) QSTEP(y, 1) QSTEP(z, 2) QSTEP(w, 3)
#undef QSTEP
            }
            #pragma unroll
            for (int c = 0; c < 12; ++c) {
                const float bb = qb[o0 + c];
                sbuf[m0 * 144 + o0 + c]       = acc0[c] + bb;
                sbuf[(m0 + 1) * 144 + o0 + c] = acc1[c] + bb;
            }
        }
        __syncthreads();

        // ---- banded attention: 4 seq x 10 i x 8 h = 320 tasks, branch-free band ----
        float ores[2][6];
        #pragma unroll
        for (int it = 0; it < 2; ++it) {
            const int task = tid + it * THREADS;
            if (task < 320) {
                const int s = task / 80, r = task % 80, i = r / 8, h = r % 8;
                const float* base = sbuf + s * 1440 + h * 6;
                const float* ki = base + i * 144 + 48;
                const float k0 = ki[0], k1 = ki[1], k2 = ki[2], k3 = ki[3], k4 = ki[4], k5 = ki[5];
                const int jm = (i > 0) ? i - 1 : 0;
                const int jp = (i < 9) ? i + 1 : 9;
                const float* qm = base + jm * 144;
                const float* qc = base + i * 144;
                const float* qp = base + jp * 144;
                const float sc = 0.4082482904638631f;  // 6^-0.5
                float s0 = (k0*qm[0]+k1*qm[1]+k2*qm[2]+k3*qm[3]+k4*qm[4]+k5*qm[5]) * sc;
                float s1 = (k0*qc[0]+k1*qc[1]+k2*qc[2]+k3*qc[3]+k4*qc[4]+k5*qc[5]) * sc;
                float s2 = (k0*qp[0]+k1*qp[1]+k2*qp[2]+k3*qp[3]+k4*qp[4]+k5*qp[5]) * sc;
                if (i == 0) s0 = -3.4e38f;
                if (i == 9) s2 = -3.4e38f;
                const float mx = fmaxf(s0, fmaxf(s1, s2));
                const float p0 = expf(s0 - mx), p1 = expf(s1 - mx), p2 = expf(s2 - mx);
                const float inv = 1.0f / (p0 + p1 + p2);
                const float* vm = qm + 96;
                const float* vc = qc + 96;
                const float* vp = qp + 96;
                #pragma unroll
                for (int d = 0; d < 6; ++d)
                    ores[it][d] = (p0 * vm[d] + p1 * vc[d] + p2 * vp[d]) * inv;
            }
        }
        __syncthreads();
        #pragma unroll
        for (int it = 0; it < 2; ++it) {
            const int task = tid + it * THREADS;
            if (task < 320) {
                const int s = task / 80, r = task % 80, i = r / 8, h = r % 8;
                float* dst = sbuf + (s * 10 + i) * TS + h * 6;
                #pragma unroll
                for (int d = 0; d < 6; ++d) dst[d] = ores[it][d];
            }
        }
        __syncthreads();

        // ---- proj + residual: 40x48, 240 tasks of 2 rows x 4 cols, K=48 ----
        if (tid < 240) {
            const int og = tid % 12, mg = tid / 12;
            const int o0 = og * 4, m0 = mg * 2;
            const float* orow = sbuf + m0 * TS;
            float acc0[4] = {0,0,0,0};
            float acc1[4] = {0,0,0,0};
            for (int k = 0; k < 48; k += 4) {
                const float4 a0 = *(const float4*)(orow + k);
                const float4 a1 = *(const float4*)(orow + TS + k);
#define PSTEP(comp, kk) { \
                const float4 w0 = *(const float4*)(pw + (k + kk) * 48 + o0); \
                FMA4(acc0, a0.comp, w0) \
                FMA4(acc1, a1.comp, w0) }
                PSTEP(x, 0) PSTEP(y, 1) PSTEP(z, 2) PSTEP(w, 3)
#undef PSTEP
            }
            #pragma unroll
            for (int c = 0; c < 4; ++c) {
                const float bb = pb[o0 + c];
                tbuf[m0 * TS + o0 + c]       += acc0[c] + bb;
                tbuf[(m0 + 1) * TS + o0 + c] += acc1[c] + bb;
            }
        }
        __syncthreads();

        // ---- ff1 + gelu: 40x192, 240 tasks of 2 rows x 16 cols, K=48 ----
        if (tid < 240) {
            const int og = tid % 12, mg = tid / 12;
            const int o0 = og * 16, m0 = mg * 2;
            const float* trow = tbuf + m0 * TS;
            float acc0[16] = {0,0,0,0,0,0,0,0,0,0,0,0,0,0,0,0};
            float acc1[16] = {0,0,0,0,0,0,0,0,0,0,0,0,0,0,0,0};
            for (int k = 0; k < 48; k += 4) {
                const float4 a0 = *(const float4*)(trow + k);
                const float4 a1 = *(const float4*)(trow + TS + k);
#define FSTEP(comp, kk) { \
                const float* wr = f1w + (k + kk) * 192 + o0; \
                const float4 w0 = *(const float4*)wr; \
                const float4 w1 = *(const float4*)(wr + 4); \
                const float4 w2 = *(const float4*)(wr + 8); \
                const float4 w3 = *(const float4*)(wr + 12); \
                FMA16(acc0, a0.comp, w0, w1, w2, w3) \
                FMA16(acc1, a1.comp, w0, w1, w2, w3) }
                FSTEP(x, 0) FSTEP(y, 1) FSTEP(z, 2) FSTEP(w, 3)
#undef FSTEP
            }
            #pragma unroll
            for (int c = 0; c < 16; ++c) {
                float v0 = acc0[c] + f1b[o0 + c];
                float v1 = acc1[c] + f1b[o0 + c];
                v0 = 0.5f * v0 * (1.f + erff(v0 * 0.70710678118654752f));
                v1 = 0.5f * v1 * (1.f + erff(v1 * 0.70710678118654752f));
                sbuf[m0 * HS + o0 + c]       = v0;
                sbuf[(m0 + 1) * HS + o0 + c] = v1;
            }
        }
        __syncthreads();

        // ---- ff2 + residual: 40x48, 240 tasks of 2 rows x 4 cols, K=192 ----
        if (tid < 240) {
            const int og = tid % 12, mg = tid / 12;
            const int o0 = og * 4, m0 = mg * 2;
            const float* hrow = sbuf + m0 * HS;
            float acc0[4] = {0,0,0,0};
            float acc1[4] = {0,0,0,0};
            for (int k = 0; k < 192; k += 4) {
                const float4 a0 = *(const float4*)(hrow + k);
                const float4 a1 = *(const float4*)(hrow + HS + k);
#define GSTEP(comp, kk) { \
                const float4 w0 = *(const float4*)(f2w + (k + kk) * 48 + o0); \
                FMA4(acc0, a0.comp, w0) \
                FMA4(acc1, a1.comp, w0) }
                GSTEP(x, 0) GSTEP(y, 1) GSTEP(z, 2) GSTEP(w, 3)
#undef GSTEP
            }
            #pragma unroll
            for (int c = 0; c < 4; ++c) {
                const float bb = f2b[o0 + c];
                tbuf[m0 * TS + o0 + c]       += acc0[c] + bb;
                tbuf[(m0 + 1) * TS + o0 + c] += acc1[c] + bb;
            }
        }
        __syncthreads();
    }

    // store: t_out[(b*4096+hw0)*480 + m*48 + f] = tbuf[m*TS + f]
    {
        float* dst = t_out + ((size_t)(b * 4096 + hw0)) * 480;
        for (int q = tid; q < 480; q += THREADS) {
            const int m = q / 12, part = (q % 12) * 4;
            *(float4*)(dst + m * 48 + part) = *(const float4*)(tbuf + m * TS + part);
        }
    }
}

// ---------------- Kernel B: depthwise 3x3 conv (SAME) + transpose to pixel-major ----------------
__global__ __launch_bounds__(THREADS) void kb_conv(
    const float* __restrict__ x, const float* __restrict__ t_in,
    const float* __restrict__ dw_w, const float* __restrict__ dw_b,
    float* __restrict__ z0)
{
    __shared__ float ct[100 * 97];     // 10x10 halo tile x 96 ch, stride 97 (bank pad)
    const int tid = threadIdx.x;
    const int blk = blockIdx.x;
    const int n = blk >> 6;            // image (b*10+c)
    const int tile = blk & 63;
    const int th0 = (tile >> 3) << 3;
    const int tw0 = (tile & 7) << 3;
    const int b = n / 10, c = n % 10;

    // x half of cat: channels 0..47, planar layout
    for (int idx = tid; idx < 4800; idx += THREADS) {
        int f = idx / 100, p = idx % 100;
        int py = p / 10, px = p % 10;
        int gh = th0 + py - 1, gw = tw0 + px - 1;
        float v = 0.f;
        if ((unsigned)gh < 64u && (unsigned)gw < 64u)
            v = x[((size_t)n * 48 + f) * 4096 + gh * 64 + gw];
        ct[p * 97 + f] = v;
    }
    // y half of cat: channels 48..95, from t (pixel-major)
    for (int idx = tid; idx < 4800; idx += THREADS) {
        int p = idx / 48, f = idx % 48;
        int py = p / 10, px = p % 10;
        int gh = th0 + py - 1, gw = tw0 + px - 1;
        float v = 0.f;
        if ((unsigned)gh < 64u && (unsigned)gw < 64u)
            v = t_in[(size_t)(b * 4096 + gh * 64 + gw) * 480 + c * 48 + f];
        ct[p * 97 + 48 + f] = v;
    }
    __syncthreads();

    #pragma unroll 4
    for (int it = 0; it < 24; ++it) {
        int oidx = tid + it * THREADS;   // 24*256 == 6144 == 64px * 96ch
        int pxl = oidx / 96, ch = oidx % 96;
        int py = pxl >> 3, pxx = pxl & 7;
        const float* wp = dw_w + ch * 9;
        float acc = dw_b[ch];
        #pragma unroll
        for (int dy = 0; dy < 3; ++dy)
            #pragma unroll
            for (int dx = 0; dx < 3; ++dx)
                acc += ct[((py + dy) * 10 + pxx + dx) * 97 + ch] * wp[dy * 3 + dx];
        z0[((size_t)n * 4096 + (th0 + py) * 64 + (tw0 + pxx)) * 96 + ch] = acc;
    }
}

// ---------------- Kernel C: LN + pw1+gelu+pw2 + shortcut, cooperative 64px/block ----------------
// LDS: zb 25.6KB + hb 25.6KB = 51.2KB -> up to 3 blocks/CU
__global__ __launch_bounds__(THREADS) void kc_mlp(
    const float* __restrict__ x, const float* __restrict__ t_in,
    const float* __restrict__ z0,
    const float* __restrict__ ln_g, const float* __restrict__ ln_b,
    const float* __restrict__ pw1_w, const float* __restrict__ pw1_b,
    const float* __restrict__ pw2_w, const float* __restrict__ pw2_b,
    const float* __restrict__ sc_w, const float* __restrict__ sc_b,
    float* __restrict__ out)
{
    __shared__ float zb[64 * 100];   // z rows (stride 100, 16B aligned); later: cat rows
    __shared__ float hb[64 * 100];   // h chunk rows (stride 100); later: out staging [f*66+px]
    const int tid = threadIdx.x;
    const int blk = blockIdx.x;       // 5120
    const int n   = blk >> 6;         // image 0..79
    const int hw0 = (blk & 63) << 6;  // 64-pixel run
    const size_t pixbase = (size_t)n * 4096 + hw0;

    // ---- stage z0 (contiguous 6144 floats) ----
    for (int idx = tid; idx < 1536; idx += THREADS) {
        float4 v = *(const float4*)(z0 + pixbase * 96 + (size_t)idx * 4);
        int p = idx / 24, c0 = (idx % 24) * 4;
        *(float4*)(&zb[p * 100 + c0]) = v;
    }
    __syncthreads();

    // ---- LayerNorm in place: one lane per pixel ----
    if (tid < 64) {
        float* r = zb + tid * 100;
        float mu = 0.f;
        #pragma unroll
        for (int k = 0; k < 96; ++k) mu += r[k];
        mu *= (1.f / 96.f);
        float var = 0.f;
        #pragma unroll
        for (int k = 0; k < 96; ++k) { float d = r[k] - mu; var += d * d; }
        var *= (1.f / 96.f);
        float rs = rsqrtf(var + 1e-6f);
        #pragma unroll
        for (int k = 0; k < 96; ++k) r[k] = (r[k] - mu) * rs * ln_g[k] + ln_b[k];
    }
    __syncthreads();

    const int pxg = tid >> 3;          // 0..31 (2 pixels each)
    const int sub = tid & 7;           // 8 col-groups
    const int f0  = sub * 6;           // phase3/shortcut cols (6 each, 48 total)

    float fa0[6], fa1[6];
    #pragma unroll
    for (int c = 0; c < 6; ++c) { fa0[c] = pw2_b[f0 + c]; fa1[c] = fa0[c]; }

    for (int jc = 0; jc < 4; ++jc) {
        // ---- phase2: h = gelu(z @ pw1[:, jc*96+...] + b), 2px x 12j per thread ----
        {
            const int j0 = jc * 96 + sub * 12;
            const float* zr = zb + pxg * 200;
            float h0[12] = {0,0,0,0,0,0,0,0,0,0,0,0};
            float h1[12] = {0,0,0,0,0,0,0,0,0,0,0,0};
            for (int k = 0; k < 96; k += 4) {
                const float4 a0 = *(const float4*)(zr + k);
                const float4 a1 = *(const float4*)(zr + 100 + k);
#define HSTEP(comp, kk) { \
                const float* wr = pw1_w + (k + kk) * 384 + j0; \
                const float4 w0 = *(const float4*)wr; \
                const float4 w1 = *(const float4*)(wr + 4); \
                const float4 w2 = *(const float4*)(wr + 8); \
                FMA12(h0, a0.comp, w0, w1, w2) \
                FMA12(h1, a1.comp, w0, w1, w2) }
                HSTEP(x, 0) HSTEP(y, 1) HSTEP(z, 2) HSTEP(w, 3)
#undef HSTEP
            }
            #pragma unroll
            for (int c = 0; c < 12; ++c) {
                float v0 = h0[c] + pw1_b[j0 + c];
                float v1 = h1[c] + pw1_b[j0 + c];
                v0 = 0.5f * v0 * (1.f + erff(v0 * 0.70710678118654752f));
                v1 = 0.5f * v1 * (1.f + erff(v1 * 0.70710678118654752f));
                hb[(pxg * 2) * 100 + sub * 12 + c]     = v0;
                hb[(pxg * 2 + 1) * 100 + sub * 12 + c] = v1;
            }
        }
        __syncthreads();

        // ---- phase3: facc += h_chunk @ pw2[jc*96+..., :], 2px x 6f per thread ----
        {
            const float* hr = hb + pxg * 200;
            for (int k = 0; k < 96; k += 4) {
                const float4 a0 = *(const float4*)(hr + k);
                const float4 a1 = *(const float4*)(hr + 100 + k);
#define P3STEP(comp, kk) { \
                const float* wr = pw2_w + (jc * 96 + k + kk) * 48 + f0; \
                const float b0 = wr[0], b1 = wr[1], b2 = wr[2], b3 = wr[3], b4 = wr[4], b5 = wr[5]; \
                FMA6S(fa0, a0.comp, b0, b1, b2, b3, b4, b5) \
                FMA6S(fa1, a1.comp, b0, b1, b2, b3, b4, b5) }
                P3STEP(x, 0) P3STEP(y, 1) P3STEP(z, 2) P3STEP(w, 3)
#undef P3STEP
            }
        }
        __syncthreads();   // hb reused by next chunk; zb re-read
    }

    // ---- stage cat (x planar ch 0..47, t pixel-major ch 48..95) into zb ----
    for (int idx = tid; idx < 768; idx += THREADS) {
        int ch = idx >> 4, p0 = (idx & 15) << 2;
        float4 v = *(const float4*)(x + ((size_t)n * 48 + ch) * 4096 + hw0 + p0);
        zb[(p0 + 0) * 100 + ch] = v.x; zb[(p0 + 1) * 100 + ch] = v.y;
        zb[(p0 + 2) * 100 + ch] = v.z; zb[(p0 + 3) * 100 + ch] = v.w;
    }
    {
        const size_t tb = ((size_t)(n / 10) * 4096 + hw0);
        const int coff = (n % 10) * 48;
        for (int idx = tid; idx < 768; idx += THREADS) {
            int p = idx / 12, u0 = (idx % 12) * 4;
            float4 v = *(const float4*)(t_in + (tb + p) * 480 + coff + u0);
            *(float4*)(&zb[p * 100 + 48 + u0]) = v;
        }
    }
    __syncthreads();

    // ---- shortcut: facc += cat @ sc_w^T (sc_w is [48 out][96 in]) ----
    {
        const float* cr = zb + pxg * 200;
        for (int k = 0; k < 96; k += 4) {
            const float4 a0 = *(const float4*)(cr + k);
            const float4 a1 = *(const float4*)(cr + 100 + k);
            const float4 wA = *(const float4*)(sc_w + (f0 + 0) * 96 + k);
            const float4 wB = *(const float4*)(sc_w + (f0 + 1) * 96 + k);
            const float4 wC = *(const float4*)(sc_w + (f0 + 2) * 96 + k);
            const float4 wD = *(const float4*)(sc_w + (f0 + 3) * 96 + k);
            const float4 wE = *(const float4*)(sc_w + (f0 + 4) * 96 + k);
            const float4 wF = *(const float4*)(sc_w + (f0 + 5) * 96 + k);
#define SCSTEP(comp) \
            FMA6S(fa0, a0.comp, wA.comp, wB.comp, wC.comp, wD.comp, wE.comp, wF.comp) \
            FMA6S(fa1, a1.comp, wA.comp, wB.comp, wC.comp, wD.comp, wE.comp, wF.comp)
            SCSTEP(x) SCSTEP(y) SCSTEP(z) SCSTEP(w)
#undef SCSTEP
        }
    }
    __syncthreads();   // zb/hb done; reuse hb for output staging

    // ---- epilogue: stage [f][px] (stride 66), then coalesced float4 stores ----
    #pragma unroll
    for (int c = 0; c < 6; ++c) {
        hb[(f0 + c) * 66 + pxg * 2]     = fa0[c] + sc_b[f0 + c];
        hb[(f0 + c) * 66 + pxg * 2 + 1] = fa1[c] + sc_b[f0 + c];
    }
    __syncthreads();
    for (int idx = tid; idx < 768; idx += THREADS) {
        int f = idx / 16, p0 = (idx % 16) * 4;
        float4 v;
        v.x = hb[f * 66 + p0]; v.y = hb[f * 66 + p0 + 1];
        v.z = hb[f * 66 + p0 + 2]; v.w = hb[f * 66 + p0 + 3];
        *(float4*)(out + ((size_t)n * 48 + f) * 4096 + hw0 + p0) = v;
    }
}

extern "C" void kernel_launch(void* const* d_in, const int* in_sizes, int n_in,
                              void* d_out, int out_size, void* d_ws, size_t ws_size,
                              hipStream_t stream) {
    const float* x      = (const float*)d_in[0];
    const float* qkv_w  = (const float*)d_in[1];
    const float* qkv_b  = (const float*)d_in[2];
    const float* proj_w = (const float*)d_in[3];
    const float* proj_b = (const float*)d_in[4];
    const float* ff1_w  = (const float*)d_in[5];
    const float* ff1_b  = (const float*)d_in[6];
    const float* ff2_w  = (const float*)d_in[7];
    const float* ff2_b  = (const float*)d_in[8];
    const float* dw_w   = (const float*)d_in[9];
    const float* dw_b   = (const float*)d_in[10];
    const float* ln_g   = (const float*)d_in[11];
    const float* ln_b   = (const float*)d_in[12];
    const float* pw1_w  = (const float*)d_in[13];
    const float* pw1_b  = (const float*)d_in[14];
    const float* pw2_w  = (const float*)d_in[15];
    const float* pw2_b  = (const float*)d_in[16];
    const float* sc_w   = (const float*)d_in[17];
    const float* sc_b   = (const float*)d_in[18];
    float* out = (float*)d_out;

    // workspace: t_final (B*H*W,10,48) = 15,728,640 f ; z0 (80*4096,96) = 31,457,280 f
    float* t_out = (float*)d_ws;
    float* z0    = t_out + 15728640ull;

    ka_transformer<<<8192, THREADS, 0, stream>>>(x, qkv_w, qkv_b, proj_w, proj_b,
                                                 ff1_w, ff1_b, ff2_w, ff2_b, t_out);
    kb_conv<<<5120, THREADS, 0, stream>>>(x, t_out, dw_w, dw_b, z0);
    kc_mlp<<<5120, THREADS, 0, stream>>>(x, t_out, z0, ln_g, ln_b,
                                         pw1_w, pw1_b, pw2_w, pw2_b, sc_w, sc_b, out);
}